// Round 25
// baseline (148.657 us; speedup 1.0000x reference)
//
#include <hip/hip_runtime.h>
#include <hip/hip_fp16.h>
#include <math.h>

#define NF 256
#define NH 128
#define NC 16
#define NB 391      // buckets of 128 nodes: 391*128 = 50048 >= 50000
#define NBLK 512    // binning blocks (passA grid part; scanR/scanCB block dim)

typedef __attribute__((ext_vector_type(8))) short bf16x8;
typedef __attribute__((ext_vector_type(4))) float f32x4;
typedef __attribute__((ext_vector_type(2))) float f32v2;

// ---- helpers ---------------------------------------------------------------
__device__ __forceinline__ unsigned f2b(float f) {            // RNE to bf16 bits
    unsigned u = __float_as_uint(f);
    return (u + 0x7FFFu + ((u >> 16) & 1u)) >> 16;
}
__device__ __forceinline__ unsigned packt(float a, float b) { // truncate pair (MFMA inputs)
    return (__float_as_uint(a) >> 16) | (__float_as_uint(b) & 0xFFFF0000u);
}
union h2u { __half2 h; unsigned u; };
__device__ __forceinline__ __half2 uh(unsigned u) { h2u c; c.u = u; return c.h; }

// ---------------------------------------------------------------------------
// prep: ONE launch fusing (a) passA bucket histogram, (b) W1 transpose->bf16,
// (c) sentinel-row zeroing (h1c row N + h2sb row N), (d) ubase[NB]=E.
__global__ void prep_kernel(const int* __restrict__ dst, int* __restrict__ hist, int E,
                            const float* __restrict__ W1, unsigned short* __restrict__ W1T,
                            unsigned* __restrict__ h1c32, unsigned* __restrict__ h2sb,
                            int* __restrict__ ubase, int N) {
    __shared__ int h[NB];
    int b = blockIdx.x, tid = threadIdx.x;
    if (b < NBLK) {                     // ---- passA ----
        for (int i = tid; i < NB; i += 256) h[i] = 0;
        __syncthreads();
        int e0 = (int)((long long)b * E / NBLK), e1 = (int)((long long)(b + 1) * E / NBLK);
        for (int e = e0 + tid; e < e1; e += 256)
            atomicAdd(&h[dst[e] >> 7], 1);
        __syncthreads();
        for (int i = tid; i < NB; i += 256) hist[b * NB + i] = h[i];
    } else {                            // ---- w1t + sentinels ----
        int idx = (b - NBLK) * 256 + tid;
        int n = idx >> 8, k = idx & 255;
        W1T[n * 256 + k] = (unsigned short)f2b(W1[(size_t)k * NH + n]);
        if (idx < 32) {                 // h1c sentinel row N (128 B = 32 u32)
            h1c32[(size_t)N * 32 + idx] = 0u;
        } else if (idx < 40) {          // h2sb sentinel row N (8 u32)
            h2sb[(size_t)N * 8 + (idx - 32)] = 0u;
        } else if (idx == 40) {
            ubase[NB] = E;
        }
    }
}

// scanR: bucketsum[k] = sum over blocks of hist[b][k].  (NBLK threads)
__global__ void scanR_kernel(const int* __restrict__ hist, int* __restrict__ bsum) {
    __shared__ int sm[NBLK];
    int k = blockIdx.x, t = threadIdx.x;
    sm[t] = hist[t * NB + k];
    __syncthreads();
    for (int off = NBLK / 2; off > 0; off >>= 1) {
        if (t < off) sm[t] += sm[t + off];
        __syncthreads();
    }
    if (t == 0) bsum[k] = sm[0];
}

// scanCB: FUSED scanB+scanC (launch count 10->8 consolidation).  Block k:
// (1) bucket prefix: ubase[k] = sum bsum[0..k-1], pbase[k] = padded prefix
//     (each block reduces its own 391-int prefix -- cheap, removes the
//     serial scanB launch); (2) per-bucket column exclusive scan across the
//     NBLK hist rows (old scanC), offset by ubase[k].
__global__ void scanCB_kernel(const int* __restrict__ bsum, int* __restrict__ hist,
                              int* __restrict__ ubase, int* __restrict__ pbase) {
    __shared__ int sr[NBLK];
    __shared__ int sp[NBLK];
    __shared__ int ubs;
    int k = blockIdx.x, t = threadIdx.x;
    int vu = (t < k) ? bsum[t] : 0;
    int vp = (t < k) ? (((vu + 7) & ~7) + 904) : 0;
    sr[t] = vu; sp[t] = vp;
    __syncthreads();
    for (int off = NBLK / 2; off > 0; off >>= 1) {
        if (t < off) { sr[t] += sr[t + off]; sp[t] += sp[t + off]; }
        __syncthreads();
    }
    if (t == 0) { ubs = sr[0]; ubase[k] = sr[0]; pbase[k] = sp[0]; }
    __syncthreads();
    int ub = ubs;
    int v = hist[t * NB + k];
    sr[t] = v;
    __syncthreads();
    for (int off = 1; off < NBLK; off <<= 1) {
        int u = (t >= off) ? sr[t - off] : 0;
        __syncthreads();
        sr[t] += u;
        __syncthreads();
    }
    hist[t * NB + k] = ub + sr[t] - v;
}

// passB: binned scatter to bucket-sorted edge words (unpadded ebuf layout).
__global__ void passB_kernel(const int* __restrict__ src, const int* __restrict__ dst,
                             const int* __restrict__ hist, unsigned* __restrict__ ebuf,
                             int E) {
    __shared__ int cur[NB];
    int b = blockIdx.x;
    for (int i = threadIdx.x; i < NB; i += 256) cur[i] = hist[b * NB + i];
    __syncthreads();
    int e0 = (int)((long long)b * E / NBLK), e1 = (int)((long long)(b + 1) * E / NBLK);
    for (int e = e0 + (int)threadIdx.x; e < e1; e += 256) {
        int d = dst[e];
        int pos = atomicAdd(&cur[d >> 7], 1);
        ebuf[pos] = ((unsigned)d << 16) | (unsigned)src[e];
    }
}

// passC: one block per bucket: per-node histogram -> PADDED layout (each
// node's range 8-aligned, length (deg+7)&~7, pads = sentinel index N whose
// feature row is zero).  Writes rowptr (padded start), degs, dis, colidx.
__global__ void passC_kernel(const unsigned* __restrict__ ebuf, const int* __restrict__ ubase,
                             const int* __restrict__ pbase, int* __restrict__ rowptr,
                             int* __restrict__ degs, float* __restrict__ dis,
                             unsigned short* __restrict__ colidx, int N) {
    __shared__ int h[128];
    __shared__ int s2[128];
    __shared__ int curp[128];
    int k = blockIdx.x, t = threadIdx.x;
    if (t < 128) h[t] = 0;
    __syncthreads();
    int e0 = ubase[k], e1 = ubase[k + 1];
    for (int e = e0 + t; e < e1; e += 256)
        atomicAdd(&h[(ebuf[e] >> 16) & 127], 1);
    __syncthreads();
    int v = (t < 128) ? h[t] : 0;
    int pd = (v + 7) & ~7;
    if (t < 128) s2[t] = pd;
    __syncthreads();
    for (int off = 1; off < 128; off <<= 1) {
        int u = (t < 128 && t >= off) ? s2[t - off] : 0;
        __syncthreads();
        if (t < 128) s2[t] += u;
        __syncthreads();
    }
    if (t < 128) {
        int start = pbase[k] + s2[t] - pd;  // 8-aligned
        int node = k * 128 + t;
        if (node < N) {
            rowptr[node] = start;
            degs[node] = v;
            dis[node] = rsqrtf((float)(v + 1));
        }
        curp[t] = start;
    }
    __syncthreads();
    for (int e = e0 + t; e < e1; e += 256) {
        unsigned w = ebuf[e];
        int dl = (w >> 16) & 127;
        int pos = atomicAdd(&curp[dl], 1);
        colidx[pos] = (unsigned short)(w & 0xFFFFu);
    }
    __syncthreads();
    if (t < 128) {
        int endp = pbase[k] + s2[t];        // start + pd
        for (int q = curp[t]; q < endp; ++q) colidx[q] = (unsigned short)N;  // sentinel
    }
}

// ---------------------------------------------------------------------------
// h1 = dis * (x @ W1) via MFMA bf16 (round-20 proven async-LDS structure).
// FP8 e4m3 store, MONOLITHIC row-major [N+1][128 fp8] (fp8 row = 128B = 2
// lines; single-pass gather costs the same 2 lines/edge as slab-split, so
// monolithic enables the agg+relu+gemm2 fusion).  Row N = sentinel zero.
__global__ __launch_bounds__(256) void gemm1_mfma_kernel(
    const float* __restrict__ x, const unsigned short* __restrict__ W1T,
    const float* __restrict__ dis, unsigned char* __restrict__ h1c, int N) {
    __shared__ char sx[32768];                 // [32 rows][64 units of 16B]
    int tid = threadIdx.x;
    int wid = tid >> 6, lane = tid & 63;

    for (int it = 0; it < 8; ++it) {
        int lr = it * 4 + wid;
        int grow = blockIdx.x * 32 + lr;
        if (grow >= N) grow = N - 1;           // wave-uniform clamp (extras discarded)
        int fsw = (lr & 7) << 1;
        const char* gp = (const char*)x + (size_t)grow * 1024 + ((lane ^ fsw) << 4);
        __builtin_amdgcn_global_load_lds(gp, sx + lr * 1024 + lane * 16, 16, 0, 0);
    }
    __syncthreads();

    int lrow = lane & 15, lk = lane >> 4;      // A-frag: row=lane&15, k-chunk=lane>>4
    int rt = wid & 1, nh = wid >> 1;           // nh in {0,1}: 64-col half
    int lr = rt * 16 + lrow;
    int fr = (lr & 7) << 1;
    const float4* lds4 = (const float4*)sx;

    bf16x8 a[8];
#pragma unroll
    for (int kk = 0; kk < 8; ++kk) {
        int v = (kk * 8 + lk * 2) ^ fr;
        float4 lo = lds4[lr * 64 + v];
        float4 hi = lds4[lr * 64 + v + 1];
        union { unsigned u[4]; bf16x8 vv; } av;
        av.u[0] = packt(lo.x, lo.y);
        av.u[1] = packt(lo.z, lo.w);
        av.u[2] = packt(hi.x, hi.y);
        av.u[3] = packt(hi.z, hi.w);
        a[kk] = av.vv;
    }

    f32x4 acc[4];
#pragma unroll
    for (int t = 0; t < 4; ++t) acc[t] = (f32x4){0.f, 0.f, 0.f, 0.f};

#pragma unroll
    for (int nt = 0; nt < 4; ++nt) {
        int n = nh * 64 + nt * 16 + lrow;      // B-frag: col=lane&15, k-chunk=lane>>4
        const unsigned short* wp = W1T + (size_t)n * 256 + lk * 8;
        bf16x8 b0 = *(const bf16x8*)(wp + 0 * 32);
        bf16x8 b1 = *(const bf16x8*)(wp + 1 * 32);
        bf16x8 b2 = *(const bf16x8*)(wp + 2 * 32);
        bf16x8 b3 = *(const bf16x8*)(wp + 3 * 32);
        bf16x8 b4 = *(const bf16x8*)(wp + 4 * 32);
        bf16x8 b5 = *(const bf16x8*)(wp + 5 * 32);
        bf16x8 b6 = *(const bf16x8*)(wp + 6 * 32);
        bf16x8 b7 = *(const bf16x8*)(wp + 7 * 32);
        acc[nt] = __builtin_amdgcn_mfma_f32_16x16x32_bf16(a[0], b0, acc[nt], 0, 0, 0);
        acc[nt] = __builtin_amdgcn_mfma_f32_16x16x32_bf16(a[1], b1, acc[nt], 0, 0, 0);
        acc[nt] = __builtin_amdgcn_mfma_f32_16x16x32_bf16(a[2], b2, acc[nt], 0, 0, 0);
        acc[nt] = __builtin_amdgcn_mfma_f32_16x16x32_bf16(a[3], b3, acc[nt], 0, 0, 0);
        acc[nt] = __builtin_amdgcn_mfma_f32_16x16x32_bf16(a[4], b4, acc[nt], 0, 0, 0);
        acc[nt] = __builtin_amdgcn_mfma_f32_16x16x32_bf16(a[5], b5, acc[nt], 0, 0, 0);
        acc[nt] = __builtin_amdgcn_mfma_f32_16x16x32_bf16(a[6], b6, acc[nt], 0, 0, 0);
        acc[nt] = __builtin_amdgcn_mfma_f32_16x16x32_bf16(a[7], b7, acc[nt], 0, 0, 0);
    }

    // C/D layout (verified m89): col = lane&15, row_in_tile = (lane>>4)*4 + r
    int rb = blockIdx.x * 32;
    int crow0 = rb + rt * 16 + lk * 4;
#pragma unroll
    for (int r = 0; r < 4; ++r) {
        int row = crow0 + r;
        if (row < N) {
            float dr = dis[row];
            size_t base = (size_t)row * 128 + nh * 64;
#pragma unroll
            for (int nt = 0; nt < 4; ++nt) {
                float v = acc[nt][r] * dr;
                int pk = __builtin_amdgcn_cvt_pk_fp8_f32(v, v, 0, 0);
                h1c[base + nt * 16 + lrow] = (unsigned char)(pk & 0xFF);
            }
        }
    }
}

// ---------------------------------------------------------------------------
// FUSED aggregation + ReLU + bias + GEMM2.  One WAVE per node: lane l owns
// u32 (l&31) of the 128B fp8 row (features 4*(l&31)..+3); halves (l>>5)
// process even/odd edges of each broadcast index word.  Single pass over
// edges (2 lines/edge, same as slab scheme) -> aggT round-trip, second
// colidx pass, and the relu_gemm2 launch all disappear.  f32 accumulate,
// cross-half shfl_xor(32) combine, in-wave GEMM2 -> h2sb.
__global__ __launch_bounds__(256) void aggfused_kernel(
    const int* __restrict__ rowptr, const int* __restrict__ degs,
    const unsigned short* __restrict__ colidx,
    const unsigned* __restrict__ h1c32, const float* __restrict__ dis,
    const float* __restrict__ b1, const float* __restrict__ W2,
    __half2* __restrict__ h2sb, int N) {
    __shared__ float sW2[NH * NC];   // 8 KB
    __shared__ float srow[4][NH];    // 2 KB
    int tid = threadIdx.x;
    for (int k = tid; k < NH * NC; k += 256) sW2[k] = W2[k];
    __syncthreads();

    int wid = tid >> 6, lane = tid & 63;
    int i = blockIdx.x * 4 + wid;    // N = 50000 = 12500*4 exactly
    if (i >= N) return;
    int c = lane & 31;               // u32 within row
    int half = lane >> 5;            // edge parity

    unsigned sv = h1c32[(size_t)i * 32 + c];   // self-loop row
    float f0 = 0.f, f1 = 0.f, f2 = 0.f, f3 = 0.f;
    int e = rowptr[i];                         // 8-aligned
    int steps = ((degs[i] + 7) >> 3) * 2;      // uint2 steps (4 edges each), even
    const unsigned* cidx32 = (const unsigned*)colidx;
    int w0i = e >> 1;                          // multiple of 4
    if (steps > 0) {
        uint2 w = *(const uint2*)(cidx32 + w0i);
        for (int s = 1; s < steps; ++s) {
            uint2 wn = *(const uint2*)(cidx32 + w0i + 2 * s);   // prefetch
            int aA = half ? (int)(w.x >> 16) : (int)(w.x & 0xFFFFu);
            int aB = half ? (int)(w.y >> 16) : (int)(w.y & 0xFFFFu);
            unsigned gA = h1c32[(size_t)aA * 32 + c];
            unsigned gB = h1c32[(size_t)aB * 32 + c];
            f32v2 dA0 = __builtin_amdgcn_cvt_pk_f32_fp8((int)gA, 0);
            f32v2 dA1 = __builtin_amdgcn_cvt_pk_f32_fp8((int)gA, 1);
            f32v2 dB0 = __builtin_amdgcn_cvt_pk_f32_fp8((int)gB, 0);
            f32v2 dB1 = __builtin_amdgcn_cvt_pk_f32_fp8((int)gB, 1);
            f0 += dA0.x + dB0.x; f1 += dA0.y + dB0.y;
            f2 += dA1.x + dB1.x; f3 += dA1.y + dB1.y;
            w = wn;
        }
        {   // final step
            int aA = half ? (int)(w.x >> 16) : (int)(w.x & 0xFFFFu);
            int aB = half ? (int)(w.y >> 16) : (int)(w.y & 0xFFFFu);
            unsigned gA = h1c32[(size_t)aA * 32 + c];
            unsigned gB = h1c32[(size_t)aB * 32 + c];
            f32v2 dA0 = __builtin_amdgcn_cvt_pk_f32_fp8((int)gA, 0);
            f32v2 dA1 = __builtin_amdgcn_cvt_pk_f32_fp8((int)gA, 1);
            f32v2 dB0 = __builtin_amdgcn_cvt_pk_f32_fp8((int)gB, 0);
            f32v2 dB1 = __builtin_amdgcn_cvt_pk_f32_fp8((int)gB, 1);
            f0 += dA0.x + dB0.x; f1 += dA0.y + dB0.y;
            f2 += dA1.x + dB1.x; f3 += dA1.y + dB1.y;
        }
    }
    // self-loop added to ONE half so the cross-half combine counts it once
    if (half == 0) {
        f32v2 s0 = __builtin_amdgcn_cvt_pk_f32_fp8((int)sv, 0);
        f32v2 s1 = __builtin_amdgcn_cvt_pk_f32_fp8((int)sv, 1);
        f0 += s0.x; f1 += s0.y; f2 += s1.x; f3 += s1.y;
    }
    f0 += __shfl_xor(f0, 32, 64);
    f1 += __shfl_xor(f1, 32, 64);
    f2 += __shfl_xor(f2, 32, 64);
    f3 += __shfl_xor(f3, 32, 64);

    float di = dis[i];
    if (half == 0) {                 // lanes 0-31 write srow (wave-internal LDS,
        int c0 = c * 4;              //  in-order DS pipe -> no barrier needed)
        srow[wid][c0 + 0] = fmaxf(di * f0 + b1[c0 + 0], 0.f);
        srow[wid][c0 + 1] = fmaxf(di * f1 + b1[c0 + 1], 0.f);
        srow[wid][c0 + 2] = fmaxf(di * f2 + b1[c0 + 2], 0.f);
        srow[wid][c0 + 3] = fmaxf(di * f3 + b1[c0 + 3], 0.f);
    }
    // in-wave GEMM2 (round-3 proven pattern): lane = q*16+j, partial over
    // c in [32q, 32q+32), then xor-16 + xor-32 reduce.
    int j = lane & 15, q = lane >> 4;
    const float* rw = srow[wid];
    float pacc = 0.f;
#pragma unroll
    for (int cc = 0; cc < 32; ++cc) {
        int c2 = q * 32 + cc;
        pacc += rw[c2] * sW2[c2 * NC + j];
    }
    pacc += __shfl_xor(pacc, 16, 64);
    pacc += __shfl_xor(pacc, 32, 64);
    float dp = di * pacc;
    float plo = __shfl(dp, (lane << 1) & 63, 64);
    float phi = __shfl(dp, ((lane << 1) | 1) & 63, 64);
    if (lane < 8) h2sb[(size_t)i * 8 + lane] = __floats2half2_rn(plo, phi);
}

// ---------------------------------------------------------------------------
// Layer 2 pull + bias + log_softmax.  4 lanes/node x uint2 (4 fp16/lane);
// softmax reduce = 2 shuffles; coalesced float4 output store.  Padded CSR.
__global__ void layer2_kernel(const int* __restrict__ rowptr, const int* __restrict__ degs,
                              const unsigned short* __restrict__ colidx,
                              const uint2* __restrict__ h2sb2, const float* __restrict__ dis,
                              const float* __restrict__ b2, float* __restrict__ out, int N) {
    int t = blockIdx.x * 256 + threadIdx.x;
    int i = t >> 2;
    if (i >= N) return;
    int j4 = t & 3;
    int e = rowptr[i];                                  // 8-aligned
    int cnt4 = (degs[i] + 3) >> 2;
    uint2 sv = h2sb2[(size_t)i * 4 + j4];               // self-loop
    __half2 acc0 = uh(sv.x), acc1 = uh(sv.y);
    if (cnt4 > 0) {
        uint2 w = *reinterpret_cast<const uint2*>(colidx + e);
        for (int b = 1; b < cnt4; ++b) {
            uint2 wn = *reinterpret_cast<const uint2*>(colidx + e + 4 * b);  // prefetch
            int a0 = w.x & 0xFFFF, a1 = w.x >> 16;
            int a2 = w.y & 0xFFFF, a3 = w.y >> 16;
            uint2 g0 = h2sb2[(size_t)a0 * 4 + j4];
            uint2 g1 = h2sb2[(size_t)a1 * 4 + j4];
            uint2 g2 = h2sb2[(size_t)a2 * 4 + j4];
            uint2 g3 = h2sb2[(size_t)a3 * 4 + j4];
            acc0 = __hadd2(acc0, __hadd2(__hadd2(uh(g0.x), uh(g1.x)),
                                         __hadd2(uh(g2.x), uh(g3.x))));
            acc1 = __hadd2(acc1, __hadd2(__hadd2(uh(g0.y), uh(g1.y)),
                                         __hadd2(uh(g2.y), uh(g3.y))));
            w = wn;
        }
        int a0 = w.x & 0xFFFF, a1 = w.x >> 16;
        int a2 = w.y & 0xFFFF, a3 = w.y >> 16;
        uint2 g0 = h2sb2[(size_t)a0 * 4 + j4];
        uint2 g1 = h2sb2[(size_t)a1 * 4 + j4];
        uint2 g2 = h2sb2[(size_t)a2 * 4 + j4];
        uint2 g3 = h2sb2[(size_t)a3 * 4 + j4];
        acc0 = __hadd2(acc0, __hadd2(__hadd2(uh(g0.x), uh(g1.x)),
                                     __hadd2(uh(g2.x), uh(g3.x))));
        acc1 = __hadd2(acc1, __hadd2(__hadd2(uh(g0.y), uh(g1.y)),
                                     __hadd2(uh(g2.y), uh(g3.y))));
    }
    float2 f0 = __half22float2(acc0);
    float2 f1 = __half22float2(acc1);
    float di = dis[i];
    float4 bb = *reinterpret_cast<const float4*>(b2 + 4 * j4);
    float l0 = di * f0.x + bb.x;
    float l1 = di * f0.y + bb.y;
    float l2 = di * f1.x + bb.z;
    float l3 = di * f1.y + bb.w;
    float m = fmaxf(fmaxf(l0, l1), fmaxf(l2, l3));
    m = fmaxf(m, __shfl_xor(m, 1, 64));
    m = fmaxf(m, __shfl_xor(m, 2, 64));
    float s = __expf(l0 - m) + __expf(l1 - m) + __expf(l2 - m) + __expf(l3 - m);
    s += __shfl_xor(s, 1, 64);
    s += __shfl_xor(s, 2, 64);
    float lse = m + __logf(s);
    float4 o = make_float4(l0 - lse, l1 - lse, l2 - lse, l3 - lse);
    *reinterpret_cast<float4*>(out + (size_t)i * NC + 4 * j4) = o;
}

// ---------------------------------------------------------------------------
extern "C" void kernel_launch(void* const* d_in, const int* in_sizes, int n_in,
                              void* d_out, int out_size, void* d_ws, size_t ws_size,
                              hipStream_t stream) {
    const float* x  = (const float*)d_in[0];
    const int*   ei = (const int*)d_in[1];
    const float* W1 = (const float*)d_in[2];
    const float* b1 = (const float*)d_in[3];
    const float* W2 = (const float*)d_in[4];
    const float* b2 = (const float*)d_in[5];
    float* out = (float*)d_out;

    const int N = in_sizes[0] / NF;   // 50000
    const int E = in_sizes[1] / 2;    // 1600000
    const int* src = ei;
    const int* dst = ei + E;

    // workspace layout (~20 MB); every consumed cell rewritten per call.
    unsigned char*  h1c    = (unsigned char*)d_ws;             // (N+1)*128 B fp8 (6.4 MB)
    __half2*        h2sb   = (__half2*)(h1c + (size_t)(N + 1) * 128); // (N+1)*8 u32
    float*          dis    = (float*)(h2sb + (size_t)(N + 1) * 8);    // N
    int*            degs   = (int*)(dis + N);                  // N
    int*            rowptr = degs + N;                         // N
    int*            hist   = rowptr + N;                       // NBLK*NB (0.8 MB)
    int*            bsum   = hist + NBLK * NB;                 // NB
    int*            ubase  = bsum + NB;                        // NB+1
    int*            pbase  = ubase + NB + 1;                   // NB+1 (+pad)
    unsigned*       ebuf   = (unsigned*)(pbase + NB + 2);      // E u32 (6.4 MB)
    unsigned short* colidx = (unsigned short*)(ebuf + E);      // E+360000 u16 (~3.9 MB)
    unsigned short* W1T    = colidx + (size_t)E + 360000;      // 32768 u16 (64 KB)

    prep_kernel<<<NBLK + 128, 256, 0, stream>>>(dst, hist, E, W1, W1T,
                                                (unsigned*)h1c, (unsigned*)h2sb,
                                                ubase, N);
    scanR_kernel<<<NB, NBLK, 0, stream>>>(hist, bsum);
    scanCB_kernel<<<NB, NBLK, 0, stream>>>(bsum, hist, ubase, pbase);
    passB_kernel<<<NBLK, 256, 0, stream>>>(src, dst, hist, ebuf, E);
    passC_kernel<<<NB, 256, 0, stream>>>(ebuf, ubase, pbase, rowptr, degs, dis, colidx, N);

    gemm1_mfma_kernel<<<(N + 31) / 32, 256, 0, stream>>>(x, W1T, dis, h1c, N);

    aggfused_kernel<<<(N + 3) / 4, 256, 0, stream>>>(rowptr, degs, colidx,
                                                     (const unsigned*)h1c, dis, b1, W2,
                                                     h2sb, N);

    layer2_kernel<<<((size_t)N * 4 + 255) / 256, 256, 0, stream>>>(rowptr, degs, colidx,
                                                                   (const uint2*)h2sb, dis, b2, out, N);
}

// Round 26
// 142.432 us; speedup vs baseline: 1.0437x; 1.0437x over previous
//
#include <hip/hip_runtime.h>
#include <hip/hip_fp16.h>
#include <math.h>

#define NF 256
#define NH 128
#define NC 16
#define NB 391      // buckets of 128 nodes: 391*128 = 50048 >= 50000
#define NBLK 512    // binning blocks (passA grid part; scanR/scanCB block dim)

typedef __attribute__((ext_vector_type(8))) short bf16x8;
typedef __attribute__((ext_vector_type(4))) float f32x4;
typedef __attribute__((ext_vector_type(2))) float f32v2;

// ---- helpers ---------------------------------------------------------------
__device__ __forceinline__ unsigned f2b(float f) {            // RNE to bf16 bits
    unsigned u = __float_as_uint(f);
    return (u + 0x7FFFu + ((u >> 16) & 1u)) >> 16;
}
__device__ __forceinline__ unsigned packt(float a, float b) { // truncate pair (MFMA inputs)
    return (__float_as_uint(a) >> 16) | (__float_as_uint(b) & 0xFFFF0000u);
}
union h2u { __half2 h; unsigned u; };
__device__ __forceinline__ __half2 uh(unsigned u) { h2u c; c.u = u; return c.h; }
__device__ __forceinline__ unsigned hu(__half2 h) { h2u c; c.h = h; return c.u; }

// ---------------------------------------------------------------------------
// prep: ONE launch fusing (a) passA bucket histogram, (b) W1 transpose->bf16,
// (c) sentinel-row zeroing (h1c 2-slab row N + h2sb row N), (d) ubase[NB]=E.
__global__ void prep_kernel(const int* __restrict__ dst, int* __restrict__ hist, int E,
                            const float* __restrict__ W1, unsigned short* __restrict__ W1T,
                            unsigned* __restrict__ h1c32, unsigned* __restrict__ h2sb,
                            int* __restrict__ ubase, int N) {
    __shared__ int h[NB];
    int b = blockIdx.x, tid = threadIdx.x;
    if (b < NBLK) {                     // ---- passA ----
        for (int i = tid; i < NB; i += 256) h[i] = 0;
        __syncthreads();
        int e0 = (int)((long long)b * E / NBLK), e1 = (int)((long long)(b + 1) * E / NBLK);
        for (int e = e0 + tid; e < e1; e += 256)
            atomicAdd(&h[dst[e] >> 7], 1);
        __syncthreads();
        for (int i = tid; i < NB; i += 256) hist[b * NB + i] = h[i];
    } else {                            // ---- w1t + sentinels ----
        int idx = (b - NBLK) * 256 + tid;
        int n = idx >> 8, k = idx & 255;
        W1T[n * 256 + k] = (unsigned short)f2b(W1[(size_t)k * NH + n]);
        if (idx < 32) {                 // h1c sentinel row N: 2 slabs x 16 u32
            int q = idx >> 4, j = idx & 15;
            h1c32[(size_t)q * (N + 1) * 16 + (size_t)N * 16 + j] = 0u;
        } else if (idx < 40) {          // h2sb sentinel row N: 8 u32
            h2sb[(size_t)N * 8 + (idx - 32)] = 0u;
        } else if (idx == 40) {
            ubase[NB] = E;
        }
    }
}

// scanR: bucketsum[k] = sum over blocks of hist[b][k].  (NBLK threads)
__global__ void scanR_kernel(const int* __restrict__ hist, int* __restrict__ bsum) {
    __shared__ int sm[NBLK];
    int k = blockIdx.x, t = threadIdx.x;
    sm[t] = hist[t * NB + k];
    __syncthreads();
    for (int off = NBLK / 2; off > 0; off >>= 1) {
        if (t < off) sm[t] += sm[t + off];
        __syncthreads();
    }
    if (t == 0) bsum[k] = sm[0];
}

// scanCB: FUSED scanB+scanC (validated round 25).  Block k:
// (1) bucket prefixes ubase[k]/pbase[k] via in-block reduction of
//     bsum[0..k-1]; (2) per-bucket column exclusive scan across the NBLK
//     hist rows (old scanC), offset by ubase[k].
__global__ void scanCB_kernel(const int* __restrict__ bsum, int* __restrict__ hist,
                              int* __restrict__ ubase, int* __restrict__ pbase) {
    __shared__ int sr[NBLK];
    __shared__ int sp[NBLK];
    __shared__ int ubs;
    int k = blockIdx.x, t = threadIdx.x;
    int vu = (t < k) ? bsum[t] : 0;
    int vp = (t < k) ? (((vu + 7) & ~7) + 904) : 0;
    sr[t] = vu; sp[t] = vp;
    __syncthreads();
    for (int off = NBLK / 2; off > 0; off >>= 1) {
        if (t < off) { sr[t] += sr[t + off]; sp[t] += sp[t + off]; }
        __syncthreads();
    }
    if (t == 0) { ubs = sr[0]; ubase[k] = sr[0]; pbase[k] = sp[0]; }
    __syncthreads();
    int ub = ubs;
    int v = hist[t * NB + k];
    sr[t] = v;
    __syncthreads();
    for (int off = 1; off < NBLK; off <<= 1) {
        int u = (t >= off) ? sr[t - off] : 0;
        __syncthreads();
        sr[t] += u;
        __syncthreads();
    }
    hist[t * NB + k] = ub + sr[t] - v;
}

// passB: binned scatter to bucket-sorted edge words (unpadded ebuf layout).
__global__ void passB_kernel(const int* __restrict__ src, const int* __restrict__ dst,
                             const int* __restrict__ hist, unsigned* __restrict__ ebuf,
                             int E) {
    __shared__ int cur[NB];
    int b = blockIdx.x;
    for (int i = threadIdx.x; i < NB; i += 256) cur[i] = hist[b * NB + i];
    __syncthreads();
    int e0 = (int)((long long)b * E / NBLK), e1 = (int)((long long)(b + 1) * E / NBLK);
    for (int e = e0 + (int)threadIdx.x; e < e1; e += 256) {
        int d = dst[e];
        int pos = atomicAdd(&cur[d >> 7], 1);
        ebuf[pos] = ((unsigned)d << 16) | (unsigned)src[e];
    }
}

// passC: one block per bucket: per-node histogram -> PADDED layout (each
// node's range 8-aligned, length (deg+7)&~7, pads = sentinel index N whose
// feature row is zero).  Writes rowptr (padded start), degs, dis, colidx.
__global__ void passC_kernel(const unsigned* __restrict__ ebuf, const int* __restrict__ ubase,
                             const int* __restrict__ pbase, int* __restrict__ rowptr,
                             int* __restrict__ degs, float* __restrict__ dis,
                             unsigned short* __restrict__ colidx, int N) {
    __shared__ int h[128];
    __shared__ int s2[128];
    __shared__ int curp[128];
    int k = blockIdx.x, t = threadIdx.x;
    if (t < 128) h[t] = 0;
    __syncthreads();
    int e0 = ubase[k], e1 = ubase[k + 1];
    for (int e = e0 + t; e < e1; e += 256)
        atomicAdd(&h[(ebuf[e] >> 16) & 127], 1);
    __syncthreads();
    int v = (t < 128) ? h[t] : 0;
    int pd = (v + 7) & ~7;
    if (t < 128) s2[t] = pd;
    __syncthreads();
    for (int off = 1; off < 128; off <<= 1) {
        int u = (t < 128 && t >= off) ? s2[t - off] : 0;
        __syncthreads();
        if (t < 128) s2[t] += u;
        __syncthreads();
    }
    if (t < 128) {
        int start = pbase[k] + s2[t] - pd;  // 8-aligned
        int node = k * 128 + t;
        if (node < N) {
            rowptr[node] = start;
            degs[node] = v;
            dis[node] = rsqrtf((float)(v + 1));
        }
        curp[t] = start;
    }
    __syncthreads();
    for (int e = e0 + t; e < e1; e += 256) {
        unsigned w = ebuf[e];
        int dl = (w >> 16) & 127;
        int pos = atomicAdd(&curp[dl], 1);
        colidx[pos] = (unsigned short)(w & 0xFFFFu);
    }
    __syncthreads();
    if (t < 128) {
        int endp = pbase[k] + s2[t];        // start + pd
        for (int q = curp[t]; q < endp; ++q) colidx[q] = (unsigned short)N;  // sentinel
    }
}

// ---------------------------------------------------------------------------
// h1 = dis * (x @ W1) via MFMA bf16 (round-20 proven async-LDS structure).
// FP8 e4m3 store, 2-slab layout: slab q = cols [64q,64q+64) as
// [(N+1) rows][64 B]; row N = sentinel zero.  (Round-24 proven: fp8 halves
// aggall's gather line-requests -> 43us -> ~25us.)
__global__ __launch_bounds__(256) void gemm1_mfma_kernel(
    const float* __restrict__ x, const unsigned short* __restrict__ W1T,
    const float* __restrict__ dis, unsigned char* __restrict__ h1c, int N) {
    __shared__ char sx[32768];                 // [32 rows][64 units of 16B]
    int tid = threadIdx.x;
    int wid = tid >> 6, lane = tid & 63;

    for (int it = 0; it < 8; ++it) {
        int lr = it * 4 + wid;
        int grow = blockIdx.x * 32 + lr;
        if (grow >= N) grow = N - 1;           // wave-uniform clamp (extras discarded)
        int fsw = (lr & 7) << 1;
        const char* gp = (const char*)x + (size_t)grow * 1024 + ((lane ^ fsw) << 4);
        __builtin_amdgcn_global_load_lds(gp, sx + lr * 1024 + lane * 16, 16, 0, 0);
    }
    __syncthreads();

    int lrow = lane & 15, lk = lane >> 4;      // A-frag: row=lane&15, k-chunk=lane>>4
    int rt = wid & 1, nh = wid >> 1;           // nh in {0,1}: 64-col half = fp8 slab
    int lr = rt * 16 + lrow;
    int fr = (lr & 7) << 1;
    const float4* lds4 = (const float4*)sx;

    bf16x8 a[8];
#pragma unroll
    for (int kk = 0; kk < 8; ++kk) {
        int v = (kk * 8 + lk * 2) ^ fr;
        float4 lo = lds4[lr * 64 + v];
        float4 hi = lds4[lr * 64 + v + 1];
        union { unsigned u[4]; bf16x8 vv; } av;
        av.u[0] = packt(lo.x, lo.y);
        av.u[1] = packt(lo.z, lo.w);
        av.u[2] = packt(hi.x, hi.y);
        av.u[3] = packt(hi.z, hi.w);
        a[kk] = av.vv;
    }

    f32x4 acc[4];
#pragma unroll
    for (int t = 0; t < 4; ++t) acc[t] = (f32x4){0.f, 0.f, 0.f, 0.f};

#pragma unroll
    for (int nt = 0; nt < 4; ++nt) {
        int n = nh * 64 + nt * 16 + lrow;      // B-frag: col=lane&15, k-chunk=lane>>4
        const unsigned short* wp = W1T + (size_t)n * 256 + lk * 8;
        bf16x8 b0 = *(const bf16x8*)(wp + 0 * 32);
        bf16x8 b1 = *(const bf16x8*)(wp + 1 * 32);
        bf16x8 b2 = *(const bf16x8*)(wp + 2 * 32);
        bf16x8 b3 = *(const bf16x8*)(wp + 3 * 32);
        bf16x8 b4 = *(const bf16x8*)(wp + 4 * 32);
        bf16x8 b5 = *(const bf16x8*)(wp + 5 * 32);
        bf16x8 b6 = *(const bf16x8*)(wp + 6 * 32);
        bf16x8 b7 = *(const bf16x8*)(wp + 7 * 32);
        acc[nt] = __builtin_amdgcn_mfma_f32_16x16x32_bf16(a[0], b0, acc[nt], 0, 0, 0);
        acc[nt] = __builtin_amdgcn_mfma_f32_16x16x32_bf16(a[1], b1, acc[nt], 0, 0, 0);
        acc[nt] = __builtin_amdgcn_mfma_f32_16x16x32_bf16(a[2], b2, acc[nt], 0, 0, 0);
        acc[nt] = __builtin_amdgcn_mfma_f32_16x16x32_bf16(a[3], b3, acc[nt], 0, 0, 0);
        acc[nt] = __builtin_amdgcn_mfma_f32_16x16x32_bf16(a[4], b4, acc[nt], 0, 0, 0);
        acc[nt] = __builtin_amdgcn_mfma_f32_16x16x32_bf16(a[5], b5, acc[nt], 0, 0, 0);
        acc[nt] = __builtin_amdgcn_mfma_f32_16x16x32_bf16(a[6], b6, acc[nt], 0, 0, 0);
        acc[nt] = __builtin_amdgcn_mfma_f32_16x16x32_bf16(a[7], b7, acc[nt], 0, 0, 0);
    }

    // C/D layout (verified m89): col = lane&15, row_in_tile = (lane>>4)*4 + r
    int rb = blockIdx.x * 32;
    int crow0 = rb + rt * 16 + lk * 4;
#pragma unroll
    for (int r = 0; r < 4; ++r) {
        int row = crow0 + r;
        if (row < N) {
            float dr = dis[row];
            size_t base = ((size_t)nh * (N + 1) + row) * 64;
#pragma unroll
            for (int nt = 0; nt < 4; ++nt) {
                float v = acc[nt][r] * dr;
                int pk = __builtin_amdgcn_cvt_pk_fp8_f32(v, v, 0, 0);
                h1c[base + nt * 16 + lrow] = (unsigned char)(pk & 0xFF);
            }
        }
    }
}

// ---------------------------------------------------------------------------
// Both agg passes in ONE dispatch (round-24 proven ~25us).  FP8 gathers:
// one 64B line request per edge per pass.  16 lanes/node (8 gathers in
// flight/lane -- the MLP depth round-25's fusion destroyed); HW
// cvt_pk_f32_fp8 unpack; f32 accumulate; fp16 aggT in relu_gemm2's layout.
__global__ __launch_bounds__(256) void aggall_kernel(
    const int* __restrict__ rowptr, const int* __restrict__ degs,
    const unsigned short* __restrict__ colidx,
    const unsigned char* __restrict__ h1c, __half2* __restrict__ aggT, int N, int bps) {
    int p = blockIdx.x / bps;                           // slab 0 or 1
    int i = (blockIdx.x - p * bps) * 16 + (threadIdx.x >> 4);
    if (i >= N) return;
    int l = threadIdx.x & 15;
    const unsigned* slab = (const unsigned*)(h1c + (size_t)p * (N + 1) * 64);
    unsigned sv = slab[(size_t)i * 16 + l];             // self-loop (4 fp8)
    f32v2 c0 = __builtin_amdgcn_cvt_pk_f32_fp8((int)sv, 0);
    f32v2 c1 = __builtin_amdgcn_cvt_pk_f32_fp8((int)sv, 1);
    float f0 = c0.x, f1 = c0.y, f2 = c1.x, f3 = c1.y;
    int e = rowptr[i];                                  // 8-aligned
    int cnt8 = (degs[i] + 7) >> 3;
    if (cnt8 > 0) {
        uint4 w = *reinterpret_cast<const uint4*>(colidx + e);
        for (int b = 1; b < cnt8; ++b) {
            uint4 wn = *reinterpret_cast<const uint4*>(colidx + e + 8 * b);  // prefetch
            int a0 = w.x & 0xFFFF, a1 = w.x >> 16, a2 = w.y & 0xFFFF, a3 = w.y >> 16;
            int a4 = w.z & 0xFFFF, a5 = w.z >> 16, a6 = w.w & 0xFFFF, a7 = w.w >> 16;
            unsigned g0 = slab[(size_t)a0 * 16 + l];
            unsigned g1 = slab[(size_t)a1 * 16 + l];
            unsigned g2 = slab[(size_t)a2 * 16 + l];
            unsigned g3 = slab[(size_t)a3 * 16 + l];
            unsigned g4 = slab[(size_t)a4 * 16 + l];
            unsigned g5 = slab[(size_t)a5 * 16 + l];
            unsigned g6 = slab[(size_t)a6 * 16 + l];
            unsigned g7 = slab[(size_t)a7 * 16 + l];
            f32v2 d;
            d = __builtin_amdgcn_cvt_pk_f32_fp8((int)g0, 0); f0 += d.x; f1 += d.y;
            d = __builtin_amdgcn_cvt_pk_f32_fp8((int)g0, 1); f2 += d.x; f3 += d.y;
            d = __builtin_amdgcn_cvt_pk_f32_fp8((int)g1, 0); f0 += d.x; f1 += d.y;
            d = __builtin_amdgcn_cvt_pk_f32_fp8((int)g1, 1); f2 += d.x; f3 += d.y;
            d = __builtin_amdgcn_cvt_pk_f32_fp8((int)g2, 0); f0 += d.x; f1 += d.y;
            d = __builtin_amdgcn_cvt_pk_f32_fp8((int)g2, 1); f2 += d.x; f3 += d.y;
            d = __builtin_amdgcn_cvt_pk_f32_fp8((int)g3, 0); f0 += d.x; f1 += d.y;
            d = __builtin_amdgcn_cvt_pk_f32_fp8((int)g3, 1); f2 += d.x; f3 += d.y;
            d = __builtin_amdgcn_cvt_pk_f32_fp8((int)g4, 0); f0 += d.x; f1 += d.y;
            d = __builtin_amdgcn_cvt_pk_f32_fp8((int)g4, 1); f2 += d.x; f3 += d.y;
            d = __builtin_amdgcn_cvt_pk_f32_fp8((int)g5, 0); f0 += d.x; f1 += d.y;
            d = __builtin_amdgcn_cvt_pk_f32_fp8((int)g5, 1); f2 += d.x; f3 += d.y;
            d = __builtin_amdgcn_cvt_pk_f32_fp8((int)g6, 0); f0 += d.x; f1 += d.y;
            d = __builtin_amdgcn_cvt_pk_f32_fp8((int)g6, 1); f2 += d.x; f3 += d.y;
            d = __builtin_amdgcn_cvt_pk_f32_fp8((int)g7, 0); f0 += d.x; f1 += d.y;
            d = __builtin_amdgcn_cvt_pk_f32_fp8((int)g7, 1); f2 += d.x; f3 += d.y;
            w = wn;
        }
        {   // final 8-block
            int a0 = w.x & 0xFFFF, a1 = w.x >> 16, a2 = w.y & 0xFFFF, a3 = w.y >> 16;
            int a4 = w.z & 0xFFFF, a5 = w.z >> 16, a6 = w.w & 0xFFFF, a7 = w.w >> 16;
            unsigned g0 = slab[(size_t)a0 * 16 + l];
            unsigned g1 = slab[(size_t)a1 * 16 + l];
            unsigned g2 = slab[(size_t)a2 * 16 + l];
            unsigned g3 = slab[(size_t)a3 * 16 + l];
            unsigned g4 = slab[(size_t)a4 * 16 + l];
            unsigned g5 = slab[(size_t)a5 * 16 + l];
            unsigned g6 = slab[(size_t)a6 * 16 + l];
            unsigned g7 = slab[(size_t)a7 * 16 + l];
            f32v2 d;
            d = __builtin_amdgcn_cvt_pk_f32_fp8((int)g0, 0); f0 += d.x; f1 += d.y;
            d = __builtin_amdgcn_cvt_pk_f32_fp8((int)g0, 1); f2 += d.x; f3 += d.y;
            d = __builtin_amdgcn_cvt_pk_f32_fp8((int)g1, 0); f0 += d.x; f1 += d.y;
            d = __builtin_amdgcn_cvt_pk_f32_fp8((int)g1, 1); f2 += d.x; f3 += d.y;
            d = __builtin_amdgcn_cvt_pk_f32_fp8((int)g2, 0); f0 += d.x; f1 += d.y;
            d = __builtin_amdgcn_cvt_pk_f32_fp8((int)g2, 1); f2 += d.x; f3 += d.y;
            d = __builtin_amdgcn_cvt_pk_f32_fp8((int)g3, 0); f0 += d.x; f1 += d.y;
            d = __builtin_amdgcn_cvt_pk_f32_fp8((int)g3, 1); f2 += d.x; f3 += d.y;
            d = __builtin_amdgcn_cvt_pk_f32_fp8((int)g4, 0); f0 += d.x; f1 += d.y;
            d = __builtin_amdgcn_cvt_pk_f32_fp8((int)g4, 1); f2 += d.x; f3 += d.y;
            d = __builtin_amdgcn_cvt_pk_f32_fp8((int)g5, 0); f0 += d.x; f1 += d.y;
            d = __builtin_amdgcn_cvt_pk_f32_fp8((int)g5, 1); f2 += d.x; f3 += d.y;
            d = __builtin_amdgcn_cvt_pk_f32_fp8((int)g6, 0); f0 += d.x; f1 += d.y;
            d = __builtin_amdgcn_cvt_pk_f32_fp8((int)g6, 1); f2 += d.x; f3 += d.y;
            d = __builtin_amdgcn_cvt_pk_f32_fp8((int)g7, 0); f0 += d.x; f1 += d.y;
            d = __builtin_amdgcn_cvt_pk_f32_fp8((int)g7, 1); f2 += d.x; f3 += d.y;
        }
    }
    __half2 h01 = __floats2half2_rn(f0, f1);
    __half2 h23 = __floats2half2_rn(f2, f3);
    size_t base = ((size_t)(p * 2 + (l >> 3)) * N + i) * 16 + ((2 * l) & 15);
    *reinterpret_cast<uint2*>(aggT + base) = make_uint2(hu(h01), hu(h23));
}

// ---------------------------------------------------------------------------
// ReLU + bias + GEMM2 from aggT (fp16).  One wave per node (4 nodes/block).
__global__ __launch_bounds__(256) void relu_gemm2_kernel(
    const __half2* __restrict__ aggT, const float* __restrict__ dis,
    const float* __restrict__ b1, const float* __restrict__ W2,
    __half2* __restrict__ h2sb, int N) {
    __shared__ float sW2[NH * NC];   // 8 KB
    __shared__ float srow[4][NH];    // 2 KB
    int tid = threadIdx.x;
    for (int k = tid; k < NH * NC; k += 256) sW2[k] = W2[k];
    __syncthreads();

    int wid = tid >> 6, lane = tid & 63;
    int i = blockIdx.x * 4 + wid;
    if (i >= N) return;
    int p = lane >> 4, l16 = lane & 15;
    float2 f = __half22float2(aggT[((size_t)p * N + i) * 16 + l16]);
    float di = dis[i];
    int c0 = p * 32 + l16 * 2;
    srow[wid][c0]     = fmaxf(di * f.x + b1[c0], 0.f);
    srow[wid][c0 + 1] = fmaxf(di * f.y + b1[c0 + 1], 0.f);
    int j = lane & 15, q = lane >> 4;
    const float* rw = srow[wid];
    float pacc = 0.f;
#pragma unroll
    for (int cc = 0; cc < 32; ++cc) {
        int c = q * 32 + cc;
        pacc += rw[c] * sW2[c * NC + j];
    }
    pacc += __shfl_xor(pacc, 16, 64);
    pacc += __shfl_xor(pacc, 32, 64);
    float dp = di * pacc;
    float plo = __shfl(dp, (lane << 1) & 63, 64);
    float phi = __shfl(dp, ((lane << 1) | 1) & 63, 64);
    if (lane < 8) h2sb[(size_t)i * 8 + lane] = __floats2half2_rn(plo, phi);
}

// ---------------------------------------------------------------------------
// Layer 2 pull + bias + log_softmax.  4 lanes/node x uint2 (4 fp16/lane);
// softmax reduce = 2 shuffles; coalesced float4 output store.  Padded CSR.
__global__ void layer2_kernel(const int* __restrict__ rowptr, const int* __restrict__ degs,
                              const unsigned short* __restrict__ colidx,
                              const uint2* __restrict__ h2sb2, const float* __restrict__ dis,
                              const float* __restrict__ b2, float* __restrict__ out, int N) {
    int t = blockIdx.x * 256 + threadIdx.x;
    int i = t >> 2;
    if (i >= N) return;
    int j4 = t & 3;
    int e = rowptr[i];                                  // 8-aligned
    int cnt4 = (degs[i] + 3) >> 2;
    uint2 sv = h2sb2[(size_t)i * 4 + j4];               // self-loop
    __half2 acc0 = uh(sv.x), acc1 = uh(sv.y);
    if (cnt4 > 0) {
        uint2 w = *reinterpret_cast<const uint2*>(colidx + e);
        for (int b = 1; b < cnt4; ++b) {
            uint2 wn = *reinterpret_cast<const uint2*>(colidx + e + 4 * b);  // prefetch
            int a0 = w.x & 0xFFFF, a1 = w.x >> 16;
            int a2 = w.y & 0xFFFF, a3 = w.y >> 16;
            uint2 g0 = h2sb2[(size_t)a0 * 4 + j4];
            uint2 g1 = h2sb2[(size_t)a1 * 4 + j4];
            uint2 g2 = h2sb2[(size_t)a2 * 4 + j4];
            uint2 g3 = h2sb2[(size_t)a3 * 4 + j4];
            acc0 = __hadd2(acc0, __hadd2(__hadd2(uh(g0.x), uh(g1.x)),
                                         __hadd2(uh(g2.x), uh(g3.x))));
            acc1 = __hadd2(acc1, __hadd2(__hadd2(uh(g0.y), uh(g1.y)),
                                         __hadd2(uh(g2.y), uh(g3.y))));
            w = wn;
        }
        int a0 = w.x & 0xFFFF, a1 = w.x >> 16;
        int a2 = w.y & 0xFFFF, a3 = w.y >> 16;
        uint2 g0 = h2sb2[(size_t)a0 * 4 + j4];
        uint2 g1 = h2sb2[(size_t)a1 * 4 + j4];
        uint2 g2 = h2sb2[(size_t)a2 * 4 + j4];
        uint2 g3 = h2sb2[(size_t)a3 * 4 + j4];
        acc0 = __hadd2(acc0, __hadd2(__hadd2(uh(g0.x), uh(g1.x)),
                                     __hadd2(uh(g2.x), uh(g3.x))));
        acc1 = __hadd2(acc1, __hadd2(__hadd2(uh(g0.y), uh(g1.y)),
                                     __hadd2(uh(g2.y), uh(g3.y))));
    }
    float2 f0 = __half22float2(acc0);
    float2 f1 = __half22float2(acc1);
    float di = dis[i];
    float4 bb = *reinterpret_cast<const float4*>(b2 + 4 * j4);
    float l0 = di * f0.x + bb.x;
    float l1 = di * f0.y + bb.y;
    float l2 = di * f1.x + bb.z;
    float l3 = di * f1.y + bb.w;
    float m = fmaxf(fmaxf(l0, l1), fmaxf(l2, l3));
    m = fmaxf(m, __shfl_xor(m, 1, 64));
    m = fmaxf(m, __shfl_xor(m, 2, 64));
    float s = __expf(l0 - m) + __expf(l1 - m) + __expf(l2 - m) + __expf(l3 - m);
    s += __shfl_xor(s, 1, 64);
    s += __shfl_xor(s, 2, 64);
    float lse = m + __logf(s);
    float4 o = make_float4(l0 - lse, l1 - lse, l2 - lse, l3 - lse);
    *reinterpret_cast<float4*>(out + (size_t)i * NC + 4 * j4) = o;
}

// ---------------------------------------------------------------------------
extern "C" void kernel_launch(void* const* d_in, const int* in_sizes, int n_in,
                              void* d_out, int out_size, void* d_ws, size_t ws_size,
                              hipStream_t stream) {
    const float* x  = (const float*)d_in[0];
    const int*   ei = (const int*)d_in[1];
    const float* W1 = (const float*)d_in[2];
    const float* b1 = (const float*)d_in[3];
    const float* W2 = (const float*)d_in[4];
    const float* b2 = (const float*)d_in[5];
    float* out = (float*)d_out;

    const int N = in_sizes[0] / NF;   // 50000
    const int E = in_sizes[1] / 2;    // 1600000
    const int* src = ei;
    const int* dst = ei + E;

    // workspace layout (~32 MB); every consumed cell rewritten per call.
    unsigned char*  h1c    = (unsigned char*)d_ws;             // 2*(N+1)*64 B fp8 (6.4 MB)
    __half2*        aggT   = (__half2*)(h1c + (size_t)2 * (N + 1) * 64); // 4*N*16 u32 (12.8 MB)
    __half2*        h2sb   = aggT + (size_t)4 * N * 16;        // (N+1)*8 u32 (sentinel row)
    float*          dis    = (float*)(h2sb + (size_t)(N + 1) * 8); // N
    int*            degs   = (int*)(dis + N);                  // N
    int*            rowptr = degs + N;                         // N
    int*            hist   = rowptr + N;                       // NBLK*NB (0.8 MB)
    int*            bsum   = hist + NBLK * NB;                 // NB
    int*            ubase  = bsum + NB;                        // NB+1
    int*            pbase  = ubase + NB + 1;                   // NB+1 (+pad)
    unsigned*       ebuf   = (unsigned*)(pbase + NB + 2);      // E u32 (6.4 MB)
    unsigned short* colidx = (unsigned short*)(ebuf + E);      // E+360000 u16 (~3.9 MB)
    unsigned short* W1T    = colidx + (size_t)E + 360000;      // 32768 u16 (64 KB)

    prep_kernel<<<NBLK + 128, 256, 0, stream>>>(dst, hist, E, W1, W1T,
                                                (unsigned*)h1c, (unsigned*)h2sb,
                                                ubase, N);
    scanR_kernel<<<NB, NBLK, 0, stream>>>(hist, bsum);
    scanCB_kernel<<<NB, NBLK, 0, stream>>>(bsum, hist, ubase, pbase);
    passB_kernel<<<NBLK, 256, 0, stream>>>(src, dst, hist, ebuf, E);
    passC_kernel<<<NB, 256, 0, stream>>>(ebuf, ubase, pbase, rowptr, degs, dis, colidx, N);

    gemm1_mfma_kernel<<<(N + 31) / 32, 256, 0, stream>>>(x, W1T, dis, h1c, N);

    const int bps = (N + 15) / 16;   // blocks per slab (16 nodes/block)
    aggall_kernel<<<2 * bps, 256, 0, stream>>>(rowptr, degs, colidx, h1c, aggT, N, bps);

    relu_gemm2_kernel<<<(N + 3) / 4, 256, 0, stream>>>(aggT, dis, b1, W2, h2sb, N);

    layer2_kernel<<<((size_t)N * 4 + 255) / 256, 256, 0, stream>>>(rowptr, degs, colidx,
                                                                   (const uint2*)h2sb, dis, b2, out, N);
}